// Round 6
// baseline (186.821 us; speedup 1.0000x reference)
//
#include <hip/hip_runtime.h>
#include <hip/hip_bf16.h>
#include <float.h>

// B=4096, D=512, N=8192, temp=0.5
#define BN_ 4096
#define DD  512
#define NN  8192
#define SCALE 2.0f   // 1/temperature

typedef unsigned short u16;
typedef __attribute__((ext_vector_type(8))) short short8;   // 8 bf16 = 4 VGPRs
typedef __attribute__((ext_vector_type(4))) float floatx4;  // MFMA acc

struct alignas(8) U16x4 { u16 x, y, z, w; };

__device__ __forceinline__ u16 f2bf(float f) {
    union { float f; unsigned u; } c; c.f = f;
    unsigned u = c.u;
    unsigned r = (u + 0x7fffu + ((u >> 16) & 1u)) >> 16;   // RNE
    return (u16)r;
}

__device__ __forceinline__ void async_copy16(const u16* g, u16* l) {
    __builtin_amdgcn_global_load_lds(
        (const __attribute__((address_space(1))) void*)g,
        (__attribute__((address_space(3))) void*)l, 16, 0, 0);
}

// ------------- kernel 1: fp32 -> bf16 concat, fused positive-pair dot -------------
__global__ __launch_bounds__(256) void convert_pos_kernel(const float* __restrict__ hi,
                                                          const float* __restrict__ hj,
                                                          u16* __restrict__ H,
                                                          float* __restrict__ out) {
    __shared__ float red[4];
    int t = blockIdx.x * 256 + threadIdx.x;     // 2048 blocks -> 524288 threads
    int e = t * 4;
    const int BD = BN_ * DD;
    float4 a = *(const float4*)(hi + e);
    float4 b = *(const float4*)(hj + e);
    U16x4 oa, ob;
    oa.x = f2bf(a.x); oa.y = f2bf(a.y); oa.z = f2bf(a.z); oa.w = f2bf(a.w);
    ob.x = f2bf(b.x); ob.y = f2bf(b.y); ob.z = f2bf(b.z); ob.w = f2bf(b.w);
    *(U16x4*)(H + e) = oa;
    *(U16x4*)(H + BD + e) = ob;
    float dot = a.x * b.x + a.y * b.y + a.z * b.z + a.w * b.w;
#pragma unroll
    for (int msk = 1; msk < 64; msk <<= 1) dot += __shfl_xor(dot, msk);
    int lane = threadIdx.x & 63, wid = threadIdx.x >> 6;
    if (lane == 0) red[wid] = dot;
    __syncthreads();
    if (threadIdx.x == 0) {
        float s = red[0] + red[1] + red[2] + red[3];
        atomicAdd(out, s * (-4.0f / (float)NN));   // -(sum pos)/N
    }
}

// ------------- kernel 2: symmetric Gram, triangle of 256x128 tiles -------------
// 1056 blocks (RI in [0,32), CJ in [0,2RI+2)). 256 threads = 4 waves; wave w
// owns rows [64w,64w+64) x 128 cols (4x8 of 16x16x32 bf16 MFMA).
// A fragments: DIRECT global loads (16 full cache lines per instr, each A
// element read by exactly one wave -> no LDS needed). B tile: LDS with 4x
// cross-wave reuse, DOUBLE-buffered so the global_load_lds prefetch for
// K-step i+1 is in flight during compute of step i (the vmcnt drain at the
// barrier then costs ~nothing). LDS chunk (row,kc) XOR-swizzled via source.
__global__ __launch_bounds__(256, 2) void gram_kernel(const u16* __restrict__ H,
                                                      float* __restrict__ Mpart,
                                                      float* __restrict__ Spart) {
    __shared__ u16 Bs[2][128 * 64];            // 2 x 16 KB
    __shared__ float Cm[4][128], Cs[4][128];   // 4 KB

    const int tid  = threadIdx.x;
    const int lane = tid & 63;
    const int wid  = tid >> 6;      // 0..3
    const int quad = lane >> 4;
    const int ln15 = lane & 15;

    // decode (RI, CJ): cumulative count before RI is RI*(RI+1)
    int t = blockIdx.x;
    int RI = (int)((sqrtf(4.0f * (float)t + 1.0f) - 1.0f) * 0.5f);
    while ((RI + 1) * (RI + 2) <= t) RI++;
    while (RI * (RI + 1) > t) RI--;
    const int CJ = t - RI * (RI + 1);           // 0 .. 2RI+1
    const bool diagX = (CJ >> 1) == RI;         // diagonal-crossing tile
    const int biBase = RI * 256, cjBase = CJ * 128;

    // B staging: 1024 chunks, 4 rounds of 256 threads
    const u16* srcB[4];
    int dstB[4];
#pragma unroll
    for (int j = 0; j < 4; j++) {
        int c   = j * 256 + tid;
        int row = c >> 3;               // 0..127
        int kc  = (c & 7) ^ (row & 7);  // swizzle inverse on source side
        srcB[j] = H + (size_t)(cjBase + row) * DD + kc * 8;
        dstB[j] = c * 8;
    }

    // A direct-load row pointers (lane ln15 -> row, quad -> k-chunk)
    const u16* aRow[4];
#pragma unroll
    for (int tm = 0; tm < 4; tm++)
        aRow[tm] = H + (size_t)(biBase + wid * 64 + tm * 16 + ln15) * DD + quad * 8;

    floatx4 acc[4][8];
#pragma unroll
    for (int i = 0; i < 4; i++)
#pragma unroll
        for (int j = 0; j < 8; j++) acc[i][j] = (floatx4)0.0f;

    // prefetch B for K-step 0 into buffer 0
#pragma unroll
    for (int j = 0; j < 4; j++) async_copy16(srcB[j], &Bs[0][dstB[j]]);

    for (int i = 0; i < 8; i++) {
        __syncthreads();                 // B(i) resident for all waves
        const int k0 = i * 64;
        if (i < 7) {                     // prefetch B(i+1) into the other buffer
            const int nxt = (i + 1) & 1;
#pragma unroll
            for (int j = 0; j < 4; j++)
                async_copy16(srcB[j] + k0 + 64, &Bs[nxt][dstB[j]]);
        }
        const u16* bs = Bs[i & 1];
#pragma unroll
        for (int kk = 0; kk < 2; kk++) {
            int ck = kk * 4 + quad;      // K-chunk 0..7
            short8 a[4], b[8];
#pragma unroll
            for (int tm = 0; tm < 4; tm++)
                a[tm] = *(const short8*)(aRow[tm] + k0 + kk * 32);
#pragma unroll
            for (int tn = 0; tn < 8; tn++) {
                int r = tn * 16 + ln15;
                b[tn] = *(const short8*)&bs[(r * 8 + (ck ^ (r & 7))) * 8];
            }
#pragma unroll
            for (int tm = 0; tm < 4; tm++)
#pragma unroll
                for (int tn = 0; tn < 8; tn++)
                    acc[tm][tn] = __builtin_amdgcn_mfma_f32_16x16x32_bf16(
                        a[tm], b[tn], acc[tm][tn], 0, 0, 0);
        }
    }

    // scale; mask self-similarity on diagonal-crossing tiles
    // C/D layout: local row = wid*64 + tm*16 + quad*4 + reg, col = tn*16 + ln15
#pragma unroll
    for (int tm = 0; tm < 4; tm++)
#pragma unroll
        for (int tn = 0; tn < 8; tn++)
#pragma unroll
            for (int r = 0; r < 4; r++) {
                float v = SCALE * acc[tm][tn][r];
                if (diagX) {
                    int grow = biBase + wid * 64 + tm * 16 + quad * 4 + r;
                    int gcol = cjBase + tn * 16 + ln15;
                    if (grow == gcol) v = -FLT_MAX;
                }
                acc[tm][tn][r] = v;
            }

    // row pass: rows wave-unique -> direct global write at slot CJ
#pragma unroll
    for (int tm = 0; tm < 4; tm++) {
#pragma unroll
        for (int r = 0; r < 4; r++) {
            float vmax = -FLT_MAX;
#pragma unroll
            for (int tn = 0; tn < 8; tn++) vmax = fmaxf(vmax, acc[tm][tn][r]);
#pragma unroll
            for (int msk = 1; msk < 16; msk <<= 1)
                vmax = fmaxf(vmax, __shfl_xor(vmax, msk));
            float s = 0.0f;
#pragma unroll
            for (int tn = 0; tn < 8; tn++) s += __expf(acc[tm][tn][r] - vmax);
#pragma unroll
            for (int msk = 1; msk < 16; msk <<= 1) s += __shfl_xor(s, msk);
            if (ln15 == 0) {
                int grow = biBase + wid * 64 + tm * 16 + quad * 4 + r;
                Mpart[(size_t)CJ * NN + grow] = vmax;
                Spart[(size_t)CJ * NN + grow] = s;
            }
        }
    }

    // col pass (transpose tile): per-col over this wave's 64 rows
    if (!diagX) {
#pragma unroll
        for (int tn = 0; tn < 8; tn++) {
            float cm = -FLT_MAX;
#pragma unroll
            for (int tm = 0; tm < 4; tm++)
#pragma unroll
                for (int r = 0; r < 4; r++) cm = fmaxf(cm, acc[tm][tn][r]);
            cm = fmaxf(cm, __shfl_xor(cm, 16));
            cm = fmaxf(cm, __shfl_xor(cm, 32));
            float s = 0.0f;
#pragma unroll
            for (int tm = 0; tm < 4; tm++)
#pragma unroll
                for (int r = 0; r < 4; r++) s += __expf(acc[tm][tn][r] - cm);
            s += __shfl_xor(s, 16);
            s += __shfl_xor(s, 32);
            if (quad == 0) {
                int y = tn * 16 + ln15;
                Cm[wid][y] = cm; Cs[wid][y] = s;
            }
        }
        __syncthreads();
        if (tid < 128) {   // merge 4 waves, write slot (CJ>>1)+RI+1
            float m = Cm[0][tid], s = Cs[0][tid];
#pragma unroll
            for (int w = 1; w < 4; w++) {
                float mw = Cm[w][tid], sw = Cs[w][tid];
                float mn = fmaxf(m, mw);
                s = s * __expf(m - mn) + sw * __expf(mw - mn);
                m = mn;
            }
            int slot = (CJ >> 1) + RI + 1;
            Mpart[(size_t)slot * NN + cjBase + tid] = m;
            Spart[(size_t)slot * NN + cjBase + tid] = s;
        }
    }
}

// ------------- kernel 3: combine slot-partials per row -> sum(lse)/N -------------
// Row r's valid slots: [0, (r>>8)+33). Block b handles rows [256b, 256b+256)
// so the trip count (b+33) is block-uniform.
__global__ __launch_bounds__(256) void lse_kernel(const float* __restrict__ Mpart,
                                                  const float* __restrict__ Spart,
                                                  float* __restrict__ out) {
    __shared__ float red[256];
    int tid = threadIdx.x;
    int r = blockIdx.x * 256 + tid;            // 32 blocks x 256 rows
    int nslots = blockIdx.x + 33;
    float m = -FLT_MAX, s = 0.0f;
    for (int c = 0; c < nslots; c++) {
        float mc = Mpart[(size_t)c * NN + r];  // coalesced
        float sc = Spart[(size_t)c * NN + r];
        float mn = fmaxf(m, mc);
        s = s * __expf(m - mn) + sc * __expf(mc - mn);
        m = mn;
    }
    float lse = m + logf(s);
    red[tid] = lse;
    __syncthreads();
    for (int st = 128; st > 0; st >>= 1) {
        if (tid < st) red[tid] += red[tid + st];
        __syncthreads();
    }
    if (tid == 0) atomicAdd(out, red[0] * (1.0f / (float)NN));
}

extern "C" void kernel_launch(void* const* d_in, const int* in_sizes, int n_in,
                              void* d_out, int out_size, void* d_ws, size_t ws_size,
                              hipStream_t stream) {
    const float* hi = (const float*)d_in[0];
    const float* hj = (const float*)d_in[1];
    float* out = (float*)d_out;

    u16*   H     = (u16*)d_ws;                                            // 8 MB
    float* Mpart = (float*)((char*)d_ws + (size_t)8 * 1024 * 1024);       // 2 MB
    float* Spart = (float*)((char*)d_ws + (size_t)10 * 1024 * 1024);      // 2 MB

    hipMemsetAsync(d_out, 0, sizeof(float), stream);

    convert_pos_kernel<<<2048, 256, 0, stream>>>(hi, hj, H, out);

    gram_kernel<<<1056, 256, 0, stream>>>(H, Mpart, Spart);   // 32*33 tiles

    lse_kernel<<<32, 256, 0, stream>>>(Mpart, Spart, out);
}

// Round 7
// 129.502 us; speedup vs baseline: 1.4426x; 1.4426x over previous
//
#include <hip/hip_runtime.h>
#include <hip/hip_bf16.h>
#include <float.h>

// B=4096, D=512, N=8192, temp=0.5
#define BN_ 4096
#define DD  512
#define NN  8192
#define SCALE 2.0f   // 1/temperature

typedef unsigned short u16;
typedef __attribute__((ext_vector_type(8))) short short8;   // 8 bf16 = 4 VGPRs
typedef __attribute__((ext_vector_type(4))) float floatx4;  // MFMA acc

struct alignas(8) U16x4 { u16 x, y, z, w; };

__device__ __forceinline__ u16 f2bf(float f) {
    union { float f; unsigned u; } c; c.f = f;
    unsigned u = c.u;
    unsigned r = (u + 0x7fffu + ((u >> 16) & 1u)) >> 16;   // RNE
    return (u16)r;
}

__device__ __forceinline__ void async_copy16(const u16* g, u16* l) {
    __builtin_amdgcn_global_load_lds(
        (const __attribute__((address_space(1))) void*)g,
        (__attribute__((address_space(3))) void*)l, 16, 0, 0);
}

// ------ kernel 1: fp32 -> bf16 concat + per-block positive-dot partial ------
// NO atomics (2048 same-address atomicAdds cost ~25 us in R3-R6): each block
// plain-stores its partial to Pos[bid]; lse_kernel reduces them. Block 0 also
// zero-inits d_out (replaces the memset dispatch; harness poisons d_out with
// 0xAA before every call).
__global__ __launch_bounds__(256) void convert_pos_kernel(const float* __restrict__ hi,
                                                          const float* __restrict__ hj,
                                                          u16* __restrict__ H,
                                                          float* __restrict__ Pos,
                                                          float* __restrict__ out) {
    __shared__ float red[4];
    int t = blockIdx.x * 256 + threadIdx.x;     // 2048 blocks -> 524288 threads
    int e = t * 4;
    const int BD = BN_ * DD;
    float4 a = *(const float4*)(hi + e);
    float4 b = *(const float4*)(hj + e);
    U16x4 oa, ob;
    oa.x = f2bf(a.x); oa.y = f2bf(a.y); oa.z = f2bf(a.z); oa.w = f2bf(a.w);
    ob.x = f2bf(b.x); ob.y = f2bf(b.y); ob.z = f2bf(b.z); ob.w = f2bf(b.w);
    *(U16x4*)(H + e) = oa;
    *(U16x4*)(H + BD + e) = ob;
    float dot = a.x * b.x + a.y * b.y + a.z * b.z + a.w * b.w;
#pragma unroll
    for (int msk = 1; msk < 64; msk <<= 1) dot += __shfl_xor(dot, msk);
    int lane = threadIdx.x & 63, wid = threadIdx.x >> 6;
    if (lane == 0) red[wid] = dot;
    __syncthreads();
    if (threadIdx.x == 0) {
        Pos[blockIdx.x] = red[0] + red[1] + red[2] + red[3];
        if (blockIdx.x == 0) *out = 0.0f;
    }
}

// ------------- kernel 2: symmetric Gram, lower-triangle 128x128 tiles -------------
// (Exact round-3 structure: best measured, 62 us.) 4 waves as 2x2 of 64x64
// wave tiles (4x4 of 16x16x32 bf16 MFMA). Row-reduce -> slot bj; col-reduce of
// the SAME accumulators -> transpose tile's partials at slot bi. LDS chunk
// (row,kc) XOR-swizzled at slot row*8 + (kc ^ (row&7)) via the source pointer.
__global__ __launch_bounds__(256, 3) void gram_kernel(const u16* __restrict__ H,
                                                      float* __restrict__ Mpart,
                                                      float* __restrict__ Spart) {
    __shared__ u16 As[128 * 64];    // 16 KB
    __shared__ u16 Bs[128 * 64];    // 16 KB
    __shared__ float Rm[2][128], Rs[2][128];   // row partials per wc
    __shared__ float Cm[2][128], Cs[2][128];   // col partials per wr

    const int tid  = threadIdx.x;
    const int lane = tid & 63;
    const int wid  = tid >> 6;
    const int quad = lane >> 4;
    const int ln15 = lane & 15;
    const int wr = wid >> 1, wc = wid & 1;

    // lower-triangle decode: blockIdx.x in [0, 2080)
    int t = blockIdx.x;
    int bi = (int)((sqrtf(8.0f * (float)t + 1.0f) - 1.0f) * 0.5f);
    while ((bi + 1) * (bi + 2) / 2 <= t) bi++;
    while (bi * (bi + 1) / 2 > t) bi--;
    const int bj = t - bi * (bi + 1) / 2;
    const bool diag = (bi == bj);
    const int biBase = bi * 128, bjBase = bj * 128;

    // staging pointers, hoisted (B source = A source + uniform delta)
    const u16* srcA[4];
    int ldsOff[4];
#pragma unroll
    for (int j = 0; j < 4; j++) {
        int c   = j * 256 + tid;        // chunk 0..1023
        int row = c >> 3;               // 0..127
        int kc  = (c & 7) ^ (row & 7);  // swizzle inverse on source side
        srcA[j]   = H + (size_t)(biBase + row) * DD + kc * 8;
        ldsOff[j] = c * 8;
    }
    const ptrdiff_t dB = (ptrdiff_t)(bjBase - biBase) * DD;

    floatx4 acc[4][4];
#pragma unroll
    for (int i = 0; i < 4; i++)
#pragma unroll
        for (int j = 0; j < 4; j++) acc[i][j] = (floatx4)0.0f;

    for (int k0 = 0; k0 < DD; k0 += 64) {
#pragma unroll
        for (int j = 0; j < 4; j++) async_copy16(srcA[j] + k0,      &As[ldsOff[j]]);
#pragma unroll
        for (int j = 0; j < 4; j++) async_copy16(srcA[j] + dB + k0, &Bs[ldsOff[j]]);
        __syncthreads();

#pragma unroll
        for (int kk = 0; kk < 2; kk++) {
            int ck = kk * 4 + quad;     // K-chunk 0..7 within the 64-wide tile
            short8 a[4], b[4];
#pragma unroll
            for (int tm = 0; tm < 4; tm++) {
                int r = wr * 64 + tm * 16 + ln15;
                a[tm] = *(const short8*)&As[(r * 8 + (ck ^ (r & 7))) * 8];
            }
#pragma unroll
            for (int tn = 0; tn < 4; tn++) {
                int r = wc * 64 + tn * 16 + ln15;
                b[tn] = *(const short8*)&Bs[(r * 8 + (ck ^ (r & 7))) * 8];
            }
#pragma unroll
            for (int tm = 0; tm < 4; tm++)
#pragma unroll
                for (int tn = 0; tn < 4; tn++)
                    acc[tm][tn] = __builtin_amdgcn_mfma_f32_16x16x32_bf16(
                        a[tm], b[tn], acc[tm][tn], 0, 0, 0);
        }
        __syncthreads();
    }

    // scale in place; mask self-similarity on diagonal tiles
    // C/D layout: local row = tm*16 + quad*4 + reg, local col = tn*16 + ln15
#pragma unroll
    for (int tm = 0; tm < 4; tm++)
#pragma unroll
        for (int tn = 0; tn < 4; tn++)
#pragma unroll
            for (int r = 0; r < 4; r++) {
                float v = SCALE * acc[tm][tn][r];
                if (diag) {
                    int lrow = wr * 64 + tm * 16 + quad * 4 + r;
                    int lcol = wc * 64 + tn * 16 + ln15;
                    if (lrow == lcol) v = -FLT_MAX;
                }
                acc[tm][tn][r] = v;
            }

    // row pass: per-row max+sumexp over this wave's 64 cols
#pragma unroll
    for (int tm = 0; tm < 4; tm++) {
#pragma unroll
        for (int r = 0; r < 4; r++) {
            float vmax = -FLT_MAX;
#pragma unroll
            for (int tn = 0; tn < 4; tn++) vmax = fmaxf(vmax, acc[tm][tn][r]);
#pragma unroll
            for (int msk = 1; msk < 16; msk <<= 1)
                vmax = fmaxf(vmax, __shfl_xor(vmax, msk));
            float s = 0.0f;
#pragma unroll
            for (int tn = 0; tn < 4; tn++) s += __expf(acc[tm][tn][r] - vmax);
#pragma unroll
            for (int msk = 1; msk < 16; msk <<= 1) s += __shfl_xor(s, msk);
            if (ln15 == 0) {
                int x = wr * 64 + tm * 16 + quad * 4 + r;
                Rm[wc][x] = vmax; Rs[wc][x] = s;
            }
        }
    }

    // col pass (transpose tile): per-col max+sumexp over this wave's 64 rows
    if (!diag) {
#pragma unroll
        for (int tn = 0; tn < 4; tn++) {
            float cm = -FLT_MAX;
#pragma unroll
            for (int tm = 0; tm < 4; tm++)
#pragma unroll
                for (int r = 0; r < 4; r++) cm = fmaxf(cm, acc[tm][tn][r]);
            cm = fmaxf(cm, __shfl_xor(cm, 16));
            cm = fmaxf(cm, __shfl_xor(cm, 32));
            float s = 0.0f;
#pragma unroll
            for (int tm = 0; tm < 4; tm++)
#pragma unroll
                for (int r = 0; r < 4; r++) s += __expf(acc[tm][tn][r] - cm);
            s += __shfl_xor(s, 16);
            s += __shfl_xor(s, 32);
            if (quad == 0) {
                int y = wc * 64 + tn * 16 + ln15;
                Cm[wr][y] = cm; Cs[wr][y] = s;
            }
        }
    }
    __syncthreads();

    // merge wave halves, write slot-major partials: Mpart[slot*NN + globalRow]
    if (tid < 128) {
        float m0 = Rm[0][tid], m1 = Rm[1][tid];
        float s0 = Rs[0][tid], s1 = Rs[1][tid];
        float m = fmaxf(m0, m1);
        float s = s0 * __expf(m0 - m) + s1 * __expf(m1 - m);
        Mpart[(size_t)bj * NN + biBase + tid] = m;
        Spart[(size_t)bj * NN + biBase + tid] = s;
    } else if (!diag) {
        int y = tid - 128;
        float m0 = Cm[0][y], m1 = Cm[1][y];
        float s0 = Cs[0][y], s1 = Cs[1][y];
        float m = fmaxf(m0, m1);
        float s = s0 * __expf(m0 - m) + s1 * __expf(m1 - m);
        Mpart[(size_t)bi * NN + bjBase + y] = m;
        Spart[(size_t)bi * NN + bjBase + y] = s;
    }
}

// ------ kernel 3: combine 64 slot-partials per row + pos partials -> loss ------
__global__ __launch_bounds__(256) void lse_kernel(const float* __restrict__ Mpart,
                                                  const float* __restrict__ Spart,
                                                  const float* __restrict__ Pos,
                                                  float* __restrict__ out) {
    __shared__ float red[256];
    int tid = threadIdx.x;
    int r = blockIdx.x * 256 + tid;            // 32 blocks x 256 rows
    float m = -FLT_MAX, s = 0.0f;
#pragma unroll 8
    for (int c = 0; c < 64; c++) {
        float mc = Mpart[(size_t)c * NN + r];  // coalesced: lane-stride 4B
        float sc = Spart[(size_t)c * NN + r];
        float mn = fmaxf(m, mc);
        s = s * __expf(m - mn) + sc * __expf(mc - mn);
        m = mn;
    }
    float v = m + logf(s);
    // fold in this block's share of the 2048 positive-dot partials
    if (tid < 64) v += -4.0f * Pos[blockIdx.x * 64 + tid];
    red[tid] = v;
    __syncthreads();
    for (int st = 128; st > 0; st >>= 1) {
        if (tid < st) red[tid] += red[tid + st];
        __syncthreads();
    }
    if (tid == 0) atomicAdd(out, red[0] * (1.0f / (float)NN));
}

extern "C" void kernel_launch(void* const* d_in, const int* in_sizes, int n_in,
                              void* d_out, int out_size, void* d_ws, size_t ws_size,
                              hipStream_t stream) {
    const float* hi = (const float*)d_in[0];
    const float* hj = (const float*)d_in[1];
    float* out = (float*)d_out;

    u16*   H     = (u16*)d_ws;                                            // 8 MB
    float* Mpart = (float*)((char*)d_ws + (size_t)8 * 1024 * 1024);       // 2 MB
    float* Spart = (float*)((char*)d_ws + (size_t)10 * 1024 * 1024);      // 2 MB
    float* Pos   = (float*)((char*)d_ws + (size_t)12 * 1024 * 1024);      // 8 KB

    convert_pos_kernel<<<2048, 256, 0, stream>>>(hi, hj, H, Pos, out);

    gram_kernel<<<2080, 256, 0, stream>>>(H, Mpart, Spart);   // 65*64/2 tiles

    lse_kernel<<<32, 256, 0, stream>>>(Mpart, Spart, Pos, out);
}